// Round 3
// baseline (297.999 us; speedup 1.0000x reference)
//
#include <hip/hip_runtime.h>
#include <math.h>

#define BB 16
#define SS 1024
#define NF 5
#define DD 64
#define HH 8
#define HDIM 8
#define NLAYER 2
#define FFD 128
#define NQ 8
#define QLAY 3
#define NC 3
#define NSWEEP 5
#define BHS_TOT (BB * HH * SS)   // 131072 = 1<<17

typedef __fp16 hf2 __attribute__((ext_vector_type(2)));
typedef __fp16 h8  __attribute__((ext_vector_type(8)));
typedef float  f4x __attribute__((ext_vector_type(4)));

// ---------------- fast cross-lane helpers (k_tail latency chain) ------------
__device__ __forceinline__ int   f2i_(float x) { union { float f; int i; } u; u.f = x; return u.i; }
__device__ __forceinline__ float i2f_(int x)   { union { float f; int i; } u; u.i = x; return u.f; }

// full-wave lane gather: value of lane (pa/4) — pa is a BYTE lane address.
__device__ __forceinline__ float bperm_(int pa, float x) {
    return i2f_(__builtin_amdgcn_ds_bpermute(pa, f2i_(x)));
}

// lane ^ 32 via v_permlane32_swap_b32 (VALU-speed). Semantics-proof select:
// of the two returned words one is the lo-half broadcast and the other the
// hi-half broadcast; the word bitwise-equal to my own value is my own half,
// so the other word is x[lane^32].
__device__ __forceinline__ float half32_(float x) {
#if defined(__has_builtin)
#if __has_builtin(__builtin_amdgcn_permlane32_swap)
    int xi = f2i_(x);
    auto r = __builtin_amdgcn_permlane32_swap(xi, xi, false, false);
    int r0 = (int)r[0], r1 = (int)r[1];
    return i2f_(r0 == xi ? r1 : r0);
#else
    return __shfl_xor(x, 32);
#endif
#else
    return __shfl_xor(x, 32);
#endif
}

// compile-time lane-xor for the small static masks used in quad reduces.
template<int M> __device__ __forceinline__ float lx(float x) {
    if constexpr (M == 0) {
        return x;
    } else if constexpr (M == 1) {       // quad_perm [1,0,3,2]
        return i2f_(__builtin_amdgcn_update_dpp(0, f2i_(x), 0xB1, 0xF, 0xF, true));
    } else if constexpr (M == 2) {       // quad_perm [2,3,0,1]
        return i2f_(__builtin_amdgcn_update_dpp(0, f2i_(x), 0x4E, 0xF, 0xF, true));
    } else if constexpr (M == 3) {       // quad_perm [3,2,1,0]
        return i2f_(__builtin_amdgcn_update_dpp(0, f2i_(x), 0x1B, 0xF, 0xF, true));
    } else if constexpr (M < 32) {       // ds_swizzle bitmode: xor<<10 | and=0x1F
        return i2f_(__builtin_amdgcn_ds_swizzle(f2i_(x), (M << 10) | 0x1F));
    } else {
        return lx<M & 31>(half32_(x));
    }
}

// ---------------- embed + positional encoding ----------------
__global__ __launch_bounds__(64) void k_embed(const float* __restrict__ x,
                                              const float* __restrict__ Wemb,
                                              const float* __restrict__ bemb,
                                              float* __restrict__ h) {
    int bs = blockIdx.x;            // 0..B*S-1
    int s  = bs & (SS - 1);
    int d  = threadIdx.x;           // 0..63
    const float* xr = x + bs * NF;
    float acc = bemb[d];
#pragma unroll
    for (int f = 0; f < NF; ++f) acc += xr[f] * Wemb[f * DD + d];
    int i = d >> 1;
    float div = expf((float)(2 * i) * (-9.210340371976184f / 64.0f));
    float ang = (float)s * div;
    float pe = (d & 1) ? cosf(ang) : sinf(ang);
    h[bs * DD + d] = acc + pe;
}

// ---------------- fused q,k,v projection (4 rows/block) ---------------------
// Outputs: qh [BHS][8] f16 (pre-scaled), kh [BHS][8] f16, vt [BH*8][S] f16.
__global__ __launch_bounds__(64) void k_qkv(const float* __restrict__ h,
                                            const float* __restrict__ Wq, const float* __restrict__ bq,
                                            const float* __restrict__ Wk, const float* __restrict__ bk,
                                            const float* __restrict__ Wv, const float* __restrict__ bv,
                                            hf2* __restrict__ qh, hf2* __restrict__ kh,
                                            hf2* __restrict__ vt, int l) {
    __shared__ float hrow[4][DD];
    int d   = threadIdx.x;
    int bs0 = blockIdx.x * 4;
#pragma unroll
    for (int r = 0; r < 4; ++r) hrow[r][d] = h[(bs0 + r) * DD + d];
    __syncthreads();
    const float* wq = Wq + l * DD * DD;
    const float* wk = Wk + l * DD * DD;
    const float* wv = Wv + l * DD * DD;
    float aq[4], ak[4], av[4];
    float bqv = bq[l * DD + d], bkv = bk[l * DD + d], bvv = bv[l * DD + d];
#pragma unroll
    for (int r = 0; r < 4; ++r) { aq[r] = bqv; ak[r] = bkv; av[r] = bvv; }
#pragma unroll 4
    for (int i = 0; i < DD; ++i) {
        float wqv = wq[i * DD + d], wkv = wk[i * DD + d], wvv = wv[i * DD + d];
#pragma unroll
        for (int r = 0; r < 4; ++r) {
            float hv = hrow[r][i];
            aq[r] += hv * wqv; ak[r] += hv * wkv; av[r] += hv * wvv;
        }
    }
    int hh = d >> 3, hd = d & 7;
    const float qs = 0.3535533906f;
    float aqp[4], akp[4];
#pragma unroll
    for (int r = 0; r < 4; ++r) { aqp[r] = __shfl_xor(aq[r], 1); akp[r] = __shfl_xor(ak[r], 1); }
    if ((hd & 1) == 0) {
#pragma unroll
        for (int r = 0; r < 4; ++r) {
            int bs = bs0 + r;
            int b = bs >> 10, s = bs & 1023;
            int bhs = ((b * HH + hh) << 10) | s;
            qh[bhs * 4 + (hd >> 1)] = __builtin_amdgcn_cvt_pkrtz(aq[r] * qs, aqp[r] * qs);
            kh[bhs * 4 + (hd >> 1)] = __builtin_amdgcn_cvt_pkrtz(ak[r], akp[r]);
        }
    }
    // V transposed: vt[(bh*8+hd)][s] halves; rows bs0..bs0+3 are consecutive s.
    {
        int b = bs0 >> 10, s0 = bs0 & 1023;
        int vrow = (b * HH + hh) * 8 + hd;
        hf2* vp = vt + vrow * 512 + (s0 >> 1);
        vp[0] = __builtin_amdgcn_cvt_pkrtz(av[0], av[1]);
        vp[1] = __builtin_amdgcn_cvt_pkrtz(av[2], av[3]);
    }
}

// ---------------- attention via MFMA (flash-style, full-t per wave) ---------
// SWAPPED-OPERAND version: QK^T computed as mfma(K, Q) with a permuted K-row
// map (key(r) = 8*(r>>2)+(r&3) [+4 for the 2nd mfma]), so that lane (m,q)
// ends up holding P[query m][keys 8q..8q+7] — exactly the PV A-fragment.
// This removes the per-iteration P LDS round-trip (8 ds_write + 2 conflicted
// ds_read_b128 + waits) that made the previous version VALU/LDS-bound
// (VALUBusy 63%, MfmaUtil 11.6%, 2.1M bank-conflict cycles/dispatch).
__global__ __launch_bounds__(256) void k_attn(const float4* __restrict__ qh4,
                                              const float4* __restrict__ kh4,
                                              const float4* __restrict__ vt4,
                                              float* __restrict__ Ao) {
    int bh  = blockIdx.x;             // 0..127
    int sb  = blockIdx.y;             // 0..15
    int tid = threadIdx.x;
    int wv  = tid >> 6;
    int L   = tid & 63;
    int m = L & 15, quad = L >> 4;
    union U { float4 f; h8 h; };
    h8 hz = {0,0,0,0,0,0,0,0};
    // Q is the B operand now (B rows = output cols = queries)
    h8 bQ = hz;
    if (quad == 0) { U u; u.f = qh4[(bh << 10) | (sb * 64 + wv * 16 + m)]; bQ = u.h; }
    // K is the A operand; A row m -> key kmap (within the 32-key chunk)
    int kmap = 8 * (m >> 2) + (m & 3);
    const float4* kbase = kh4 + (bh << 10);
    const float4* vbase = vt4 + ((bh * 8 + m) << 7);   // only meaningful m<8
    f4x Oacc = {0.f, 0.f, 0.f, 0.f};
    float ls = 0.f;                   // partial softmax denom: query m, keys 8q..8q+7 per chunk
    for (int kc = 0; kc < 32; ++kc) {
        h8 aK0 = hz, aK1 = hz;
        if (quad == 0) {
            U u0, u1;
            u0.f = kbase[kc * 32 + kmap];
            u1.f = kbase[kc * 32 + kmap + 4];
            aK0 = u0.h; aK1 = u1.h;
        }
        f4x S0 = {0.f,0.f,0.f,0.f}, S1 = {0.f,0.f,0.f,0.f};
        S0 = __builtin_amdgcn_mfma_f32_16x16x32_f16(aK0, bQ, S0, 0, 0, 0);
        S1 = __builtin_amdgcn_mfma_f32_16x16x32_f16(aK1, bQ, S1, 0, 0, 0);
        // lane (m,q): S0[i] = S[query m][key 8q+i], S1[i] = S[query m][key 8q+4+i]
        float p0 = __expf(S0[0]), p1 = __expf(S0[1]);
        float p2 = __expf(S0[2]), p3 = __expf(S0[3]);
        float p4 = __expf(S1[0]), p5 = __expf(S1[1]);
        float p6 = __expf(S1[2]), p7 = __expf(S1[3]);
        ls += (p0 + p1 + p2 + p3) + (p4 + p5 + p6 + p7);
        hf2 c0 = __builtin_amdgcn_cvt_pkrtz(p0, p1);
        hf2 c1 = __builtin_amdgcn_cvt_pkrtz(p2, p3);
        hf2 c2 = __builtin_amdgcn_cvt_pkrtz(p4, p5);
        hf2 c3 = __builtin_amdgcn_cvt_pkrtz(p6, p7);
        h8 aP;
        aP[0] = c0[0]; aP[1] = c0[1]; aP[2] = c1[0]; aP[3] = c1[1];
        aP[4] = c2[0]; aP[5] = c2[1]; aP[6] = c3[0]; aP[7] = c3[1];
        h8 bV = hz;
        if (m < 8) {
            U uv; uv.f = vbase[kc * 4 + quad];
            bV = uv.h;
        }
        Oacc = __builtin_amdgcn_mfma_f32_16x16x32_f16(aP, bV, Oacc, 0, 0, 0);
    }
    // full row sums: reduce partials over the quad bits (lane bits 4,5)
    ls += __shfl_xor(ls, 16);
    ls += __shfl_xor(ls, 32);
    // Oacc[i] is O[query 4*quad+i][d=m]; its denom lives on lane 4*quad+i
    float d0 = bperm_((4 * quad + 0) << 2, ls);
    float d1 = bperm_((4 * quad + 1) << 2, ls);
    float d2 = bperm_((4 * quad + 2) << 2, ls);
    float d3 = bperm_((4 * quad + 3) << 2, ls);
    if (m < 8) {
        int srow = sb * 64 + wv * 16 + quad * 4;
        int base = (((bh << 10) | srow) << 3) + m;
        Ao[base]      = Oacc[0] / d0;
        Ao[base + 8]  = Oacc[1] / d1;
        Ao[base + 16] = Oacc[2] / d2;
        Ao[base + 24] = Oacc[3] / d3;
    }
}

// ---------------- fused mid: Oproj + LN1 + FFN1 + FFN2 + LN2 ----------------
__global__ __launch_bounds__(128) void k_mid(const float* __restrict__ Ao,
                                             const float* __restrict__ Wo, const float* __restrict__ bo,
                                             const float* __restrict__ g1, const float* __restrict__ b1,
                                             const float* __restrict__ Wf1, const float* __restrict__ bf1,
                                             const float* __restrict__ Wf2, const float* __restrict__ bf2,
                                             const float* __restrict__ g2, const float* __restrict__ b2,
                                             float* __restrict__ h, int l) {
    __shared__ float orow[4][DD];
    __shared__ float h1s[4][DD];
    __shared__ float frow[4][FFD];
    int t    = threadIdx.x;
    int d    = t & 63;
    int half = t >> 6;
    int bs0  = blockIdx.x * 4;
    int hh = d >> 3, hd = d & 7;
    int r0 = half * 2, r1 = r0 + 1;

#pragma unroll
    for (int rr = 0; rr < 2; ++rr) {
        int r  = r0 + rr;
        int bs = bs0 + r;
        int b = bs >> 10, s = bs & 1023;
        int bhs = ((b * HH + hh) << 10) | s;
        orow[r][d] = Ao[(bhs << 3) + hd];
    }
    __syncthreads();

    {
        const float* w = Wo + l * DD * DD;
        float bias = bo[l * DD + d];
        float acc0 = bias, acc1 = bias;
#pragma unroll 4
        for (int i = 0; i < DD; ++i) {
            float wv = w[i * DD + d];
            acc0 += orow[r0][i] * wv;
            acc1 += orow[r1][i] * wv;
        }
        float gg = g1[l * DD + d], bb = b1[l * DD + d];
        float accs[2] = {acc0, acc1};
#pragma unroll
        for (int rr = 0; rr < 2; ++rr) {
            int r = r0 + rr;
            float a = accs[rr] + h[(bs0 + r) * DD + d];
            float sum = a;
            for (int off = 32; off; off >>= 1) sum += __shfl_xor(sum, off);
            float mean = sum * (1.f / 64.f);
            float dx = a - mean;
            float vs = dx * dx;
            for (int off = 32; off; off >>= 1) vs += __shfl_xor(vs, off);
            float rstd = rsqrtf(vs * (1.f / 64.f) + 1e-5f);
            h1s[r][d] = dx * rstd * gg + bb;
        }
    }
    __syncthreads();

    {
        const float* w = Wf1 + l * DD * FFD;
        float bv = bf1[l * FFD + t];
        float a0 = bv, a1 = bv, a2 = bv, a3 = bv;
#pragma unroll 4
        for (int i = 0; i < DD; ++i) {
            float wv = w[i * FFD + t];
            a0 += h1s[0][i]*wv; a1 += h1s[1][i]*wv;
            a2 += h1s[2][i]*wv; a3 += h1s[3][i]*wv;
        }
        frow[0][t] = fmaxf(a0, 0.f); frow[1][t] = fmaxf(a1, 0.f);
        frow[2][t] = fmaxf(a2, 0.f); frow[3][t] = fmaxf(a3, 0.f);
    }
    __syncthreads();

    {
        const float* w = Wf2 + l * FFD * DD;
        float bias = bf2[l * DD + d];
        float acc0 = bias, acc1 = bias;
#pragma unroll 4
        for (int i = 0; i < FFD; ++i) {
            float wv = w[i * DD + d];
            acc0 += frow[r0][i] * wv;
            acc1 += frow[r1][i] * wv;
        }
        float gg = g2[l * DD + d], bb = b2[l * DD + d];
        float accs[2] = {acc0, acc1};
#pragma unroll
        for (int rr = 0; rr < 2; ++rr) {
            int r = r0 + rr;
            float a = accs[rr] + h1s[r][d];
            float sum = a;
            for (int off = 32; off; off >>= 1) sum += __shfl_xor(sum, off);
            float mean = sum * (1.f / 64.f);
            float dx = a - mean;
            float vs = dx * dx;
            for (int off = 32; off; off >>= 1) vs += __shfl_xor(vs, off);
            float rstd = rsqrtf(vs * (1.f / 64.f) + 1e-5f);
            h[(bs0 + r) * DD + d] = dx * rstd * gg + bb;
        }
    }
}

// ---------------- mean pool over sequence (8-way split) ----------------
__global__ __launch_bounds__(64) void k_pool(const float* __restrict__ h, float* __restrict__ pp) {
    int b = blockIdx.x, c = blockIdx.y, d = threadIdx.x;
    const float* hp = h + (b * SS + c * 128) * DD + d;
    float acc = 0.f;
#pragma unroll 8
    for (int s = 0; s < 128; ++s) acc += hp[s * DD];
    pp[(b * 8 + c) * DD + d] = acc;
}

// ---------------- fused tail: head + quantum circuit + eigensolver ----------
// SMALL-CODE version: table-driven rolled gate loop (ds_bpermute with runtime
// masks), rolled CNOT/reduce/Jacobi loops. I$-resident body.
__global__ __launch_bounds__(64) void k_tail(const float* __restrict__ pp,
                                             const float* __restrict__ Wp1, const float* __restrict__ bp1,
                                             const float* __restrict__ Wp2, const float* __restrict__ bp2,
                                             const float* __restrict__ qw,
                                             float* __restrict__ out) {
    __shared__ float pool_s[DD];
    __shared__ float hid[32];
    __shared__ float ang_s[NQ];
    __shared__ float ucoef[QLAY * 16][8];
    __shared__ float2 Ps2[256];
    int b = blockIdx.x; int L = threadIdx.x;
    int lb4 = L << 2;                 // my lane byte address for bpermute

    // ---- head ----
    {
        float acc = 0.f;
#pragma unroll
        for (int c = 0; c < 8; ++c) acc += pp[(b * 8 + c) * DD + L];
        pool_s[L] = acc * (1.f / 1024.f);
    }
    __syncthreads();
    if (L < 32) {
        float a = bp1[L];
#pragma unroll 8
        for (int i = 0; i < DD; ++i) a += pool_s[i] * Wp1[i * 32 + L];
        hid[L] = fmaxf(a, 0.f);
    }
    __syncthreads();
    if (L < NQ) {
        float a = bp2[L];
#pragma unroll 8
        for (int j = 0; j < 32; ++j) a += hid[j] * Wp2[j * NQ + L];
        ang_s[L] = tanhf(a) * 3.14159265358979f;
    }
    __syncthreads();

    // ---- per-gate 2x2 matrix table (lane-parallel, one-shot) ----
    // gate index = l*16 + g8; g8<8 -> RX(wire g8), g8>=8 -> Rot(wire g8-8).
    if (L < QLAY * 16) {
        int l = L >> 4, g8 = L & 15, w = g8 & 7;
        float u00r, u00i, u01r, u01i, u10r, u10i, u11r, u11i;
        if (g8 < 8) {
            float ha = 0.5f * ang_s[w];
            float c = __cosf(ha), s = __sinf(ha);
            u00r = c;   u00i = 0.f; u01r = 0.f; u01i = -s;
            u10r = 0.f; u10i = -s;  u11r = c;   u11i = 0.f;
        } else {
            const float* p3 = qw + (l * NQ + w) * 3;
            float phi = p3[0], th = p3[1], om = p3[2];
            float ct = __cosf(0.5f * th), st = __sinf(0.5f * th);
            float al = 0.5f * (phi + om), be = 0.5f * (phi - om);
            float ca = __cosf(al), sa = __sinf(al), cb = __cosf(be), sb = __sinf(be);
            u00r =  ct * ca; u00i = -ct * sa;
            u01r = -st * cb; u01i = -st * sb;
            u10r =  st * cb; u10i = -st * sb;
            u11r =  ct * ca; u11i =  ct * sa;
        }
        float* up = ucoef[L];
        up[0] = u00r; up[1] = u00i; up[2] = u01r; up[3] = u01i;
        up[4] = u10r; up[5] = u10i; up[6] = u11r; up[7] = u11i;
    }
    __syncthreads();

    // ---- quantum circuit (rolled, table-driven) ----
    // amp index bits: [p7 p6] = register index (bit1,bit0), [p5..p0] = lane.
    float ar[4], ai[4];
#pragma unroll
    for (int r = 0; r < 4; ++r) { ar[r] = 0.f; ai[r] = 0.f; }
    if (L == 0) ar[0] = 1.f;

#pragma unroll 1
    for (int l = 0; l < QLAY; ++l) {
#pragma unroll 1
        for (int g8 = 0; g8 < 16; ++g8) {
            const float* up = ucoef[(l << 4) | g8];
            float u00r = up[0], u00i = up[1], u01r = up[2], u01i = up[3];
            float u10r = up[4], u10i = up[5], u11r = up[6], u11i = up[7];
            int p = 7 - (g8 & 7);
            if (p >= 6) {
                // register-pair gate: p7 -> pairs (0,2),(1,3); p6 -> (0,1),(2,3)
#pragma unroll
                for (int pi_ = 0; pi_ < 2; ++pi_) {
                    int lo = (p == 7) ? pi_ : pi_ * 2;
                    int hi = (p == 7) ? pi_ + 2 : pi_ * 2 + 1;
                    float r0 = ar[lo], m0 = ai[lo], r1 = ar[hi], m1 = ai[hi];
                    ar[lo] = u00r*r0 - u00i*m0 + u01r*r1 - u01i*m1;
                    ai[lo] = u00r*m0 + u00i*r0 + u01r*m1 + u01i*r1;
                    ar[hi] = u10r*r0 - u10i*m0 + u11r*r1 - u11i*m1;
                    ai[hi] = u10r*m0 + u10i*r0 + u11r*m1 + u11i*r1;
                }
            } else {
                // cross-lane gate, runtime mask via bpermute
                int pa  = lb4 ^ (4 << p);
                int bit = (L >> p) & 1;
                float car = bit ? u11r : u00r, cai = bit ? u11i : u00i;
                float cpr = bit ? u10r : u01r, cpi = bit ? u10i : u01i;
#pragma unroll
                for (int r = 0; r < 4; ++r) {
                    float pre = bperm_(pa, ar[r]);
                    float pim = bperm_(pa, ai[r]);
                    float nr = car*ar[r] - cai*ai[r] + cpr*pre - cpi*pim;
                    float ni = car*ai[r] + cai*ar[r] + cpr*pim + cpi*pre;
                    ar[r] = nr; ai[r] = ni;
                }
            }
        }
        // ---- CNOT ladder ----
        // w=0: c=p7,t=p6 (register): swap r2<->r3
        { float t0=ar[2]; ar[2]=ar[3]; ar[3]=t0; t0=ai[2]; ai[2]=ai[3]; ai[3]=t0; }
        // w=1: c=p6(reg bit0), t=p5(lane bit5): exchange halves for r=1,3
        ar[1] = half32_(ar[1]); ai[1] = half32_(ai[1]);
        ar[3] = half32_(ar[3]); ai[3] = half32_(ai[3]);
        // w=2..6: lane-lane conditional swap, rolled
#pragma unroll 1
        for (int w = 2; w <= 6; ++w) {
            int pc = 7 - w, pt = 6 - w;
            int pa = lb4 ^ (4 << pt);
            bool ctrl = (L >> pc) & 1;
#pragma unroll
            for (int r = 0; r < 4; ++r) {
                float swr = bperm_(pa, ar[r]);
                float swi = bperm_(pa, ai[r]);
                ar[r] = ctrl ? swr : ar[r];
                ai[r] = ctrl ? swi : ai[r];
            }
        }
        // w=7: c=p0(lane bit0), t=p7(reg bit1): ctrl lanes swap (0,2),(1,3)
        {
            bool ctrl = L & 1;
            float n0r = ctrl ? ar[2] : ar[0], n2r = ctrl ? ar[0] : ar[2];
            float n0i = ctrl ? ai[2] : ai[0], n2i = ctrl ? ai[0] : ai[2];
            float n1r = ctrl ? ar[3] : ar[1], n3r = ctrl ? ar[1] : ar[3];
            float n1i = ctrl ? ai[3] : ai[1], n3i = ctrl ? ai[1] : ai[3];
            ar[0]=n0r; ar[1]=n1r; ar[2]=n2r; ar[3]=n3r;
            ai[0]=n0i; ai[1]=n1i; ai[2]=n2i; ai[3]=n3i;
        }
    }

    // ---- <Z_w>, w=0..2 (rolled bpermute reduce) ----
    {
        float p0 = ar[0]*ar[0]+ai[0]*ai[0];
        float p1 = ar[1]*ar[1]+ai[1]*ai[1];
        float p2 = ar[2]*ar[2]+ai[2]*ai[2];
        float p3 = ar[3]*ar[3]+ai[3]*ai[3];
        float z0 = p0 + p1 - p2 - p3;
        float z1 = p0 - p1 + p2 - p3;
        float zs = p0 + p1 + p2 + p3;
        float z2 = (L & 32) ? -zs : zs;
#pragma unroll 1
        for (int off = 1; off < 64; off <<= 1) {
            int pa = lb4 ^ (off << 2);
            z0 += bperm_(pa, z0);
            z1 += bperm_(pa, z1);
            z2 += bperm_(pa, z2);
        }
        if (L == 0) {
            out[b * NC + 0] = z0;
            out[b * NC + 1] = z1;
            out[b * NC + 2] = z2;
        }
    }

    // ---- hand off psi through LDS, redistribute to column layout ----
#pragma unroll
    for (int r = 0; r < 4; ++r) Ps2[(r << 6) | L] = make_float2(ar[r], ai[r]);
    __syncthreads();
    int c   = L >> 2;                 // my column
    int seg = L & 3;                  // my segment (4 elements)
    float gr[4], gi[4];
#pragma unroll
    for (int j = 0; j < 4; ++j) {
        float2 t = Ps2[(seg * 4 + j) * 16 + c];
        gr[j] = t.x; gi[j] = t.y;
    }
    float alm = 0.f;
#pragma unroll
    for (int j = 0; j < 4; ++j) alm += gr[j]*gr[j] + gi[j]*gi[j];
    alm += lx<1>(alm);
    alm += lx<2>(alm);

    // ---- one-sided Jacobi: rolled XOR tournament (runtime-mask bpermute),
    //      DPP quad reduces, native sqrt/rcp/rsq on rotation scalars ----
#pragma unroll 1
    for (int sweep = 0; sweep < NSWEEP; ++sweep) {
#pragma unroll 1
        for (int m = 1; m <= 15; ++m) {
            int pa = lb4 ^ (m << 4);  // column xor mask m -> lane xor 4m
            float pgr[4], pgi[4];
#pragma unroll
            for (int j = 0; j < 4; ++j) {
                pgr[j] = bperm_(pa, gr[j]);
                pgi[j] = bperm_(pa, gi[j]);
            }
            float bep = bperm_(pa, alm);   // partner norm
            float d = 0.f, e = 0.f;
#pragma unroll
            for (int j = 0; j < 4; ++j) {
                d += gr[j]*pgr[j] + gi[j]*pgi[j];   // Re(mine^H partner)
                e += gr[j]*pgi[j] - gi[j]*pgr[j];   // Im(mine^H partner)
            }
            d += lx<1>(d); e += lx<1>(e);           // DPP quad reduce
            d += lx<2>(d); e += lx<2>(e);
            float g2 = d*d + e*e;
            float cth = 1.f, sth = 0.f, cph = 1.f, sph = 0.f, gn = 0.f;
            if (g2 > 1e-26f) {
                gn = __builtin_amdgcn_sqrtf(g2);
                float ginv = __builtin_amdgcn_rcpf(gn);
                cph = d * ginv; sph = -e * ginv;    // conj(gamma)/|gamma|
                float tau = (alm - bep) * (0.5f * ginv);
                float t = ((tau >= 0.f) ? 1.f : -1.f) *
                          __builtin_amdgcn_rcpf(fabsf(tau) + __builtin_amdgcn_sqrtf(1.f + tau*tau));
                cth = __builtin_amdgcn_rsqf(1.f + t*t);
                sth = t * cth;
            }
#pragma unroll
            for (int j = 0; j < 4; ++j) {
                float er = cph*pgr[j] - sph*pgi[j];
                float ei = cph*pgi[j] + sph*pgr[j];
                gr[j] = cth * gr[j] + sth * er;
                gi[j] = cth * gi[j] + sth * ei;
            }
            alm = cth*cth*alm + sth*sth*bep + 2.f*cth*sth*gn;
        }
    }

    // exact final column norm (kills approx-math drift in the running alm)
    float alm2 = 0.f;
#pragma unroll
    for (int j = 0; j < 4; ++j) alm2 += gr[j]*gr[j] + gi[j]*gi[j];
    alm2 += lx<1>(alm2);
    alm2 += lx<2>(alm2);

    float ev = fminf(fmaxf(alm2, 1e-10f), 1.0f);
    float term = -ev * __logf(ev);
#pragma unroll 1
    for (int off = 4; off < 64; off <<= 1) term += bperm_(lb4 ^ (off << 2), term);
    if (L == 0) out[BB * NC + b] = term;
}

extern "C" void kernel_launch(void* const* d_in, const int* in_sizes, int n_in,
                              void* d_out, int out_size, void* d_ws, size_t ws_size,
                              hipStream_t stream) {
    const float* x    = (const float*)d_in[0];
    const float* Wemb = (const float*)d_in[1];
    const float* bemb = (const float*)d_in[2];
    const float* Wq   = (const float*)d_in[3];
    const float* bq   = (const float*)d_in[4];
    const float* Wk   = (const float*)d_in[5];
    const float* bk   = (const float*)d_in[6];
    const float* Wv   = (const float*)d_in[7];
    const float* bv   = (const float*)d_in[8];
    const float* Wo   = (const float*)d_in[9];
    const float* bo   = (const float*)d_in[10];
    const float* ln1g = (const float*)d_in[11];
    const float* ln1b = (const float*)d_in[12];
    const float* ln2g = (const float*)d_in[13];
    const float* ln2b = (const float*)d_in[14];
    const float* Wf1  = (const float*)d_in[15];
    const float* bf1  = (const float*)d_in[16];
    const float* Wf2  = (const float*)d_in[17];
    const float* bf2  = (const float*)d_in[18];
    const float* Wp1  = (const float*)d_in[19];
    const float* bp1  = (const float*)d_in[20];
    const float* Wp2  = (const float*)d_in[21];
    const float* bp2  = (const float*)d_in[22];
    const float* qwts = (const float*)d_in[23];
    float* out = (float*)d_out;

    const size_t M = 1u << 20;           // 1M floats = B*S*D
    float* ws   = (float*)d_ws;
    float* h    = ws;                            // 1M floats
    hf2*   qh   = (hf2*)(ws + M);                // 0.5M floats (BHS*8 halves)
    hf2*   kh   = (hf2*)(ws + M + M / 2);        // 0.5M floats
    hf2*   vt   = (hf2*)(ws + 2 * M);            // 0.5M floats
    float* Ao   = ws + 2 * M + M / 2;            // 1M floats (BHS*8)
    float* pp   = ws + 3 * M + M / 2;            // [16][8][64]

    k_embed<<<BB * SS, 64, 0, stream>>>(x, Wemb, bemb, h);
    for (int l = 0; l < NLAYER; ++l) {
        k_qkv<<<BB * SS / 4, 64, 0, stream>>>(h, Wq, bq, Wk, bk, Wv, bv, qh, kh, vt, l);
        k_attn<<<dim3(BB * HH, 16), 256, 0, stream>>>((const float4*)qh, (const float4*)kh,
                                                      (const float4*)vt, Ao);
        k_mid<<<BB * SS / 4, 128, 0, stream>>>(Ao, Wo, bo, ln1g, ln1b,
                                               Wf1, bf1, Wf2, bf2, ln2g, ln2b, h, l);
    }
    k_pool<<<dim3(BB, 8), 64, 0, stream>>>(h, pp);
    k_tail<<<BB, 64, 0, stream>>>(pp, Wp1, bp1, Wp2, bp2, qwts, out);
}

// Round 4
// 287.735 us; speedup vs baseline: 1.0357x; 1.0357x over previous
//
#include <hip/hip_runtime.h>
#include <math.h>

#define BB 16
#define SS 1024
#define NF 5
#define DD 64
#define HH 8
#define HDIM 8
#define NLAYER 2
#define FFD 128
#define NQ 8
#define QLAY 3
#define NC 3
#define NSWEEP 5
#define BHS_TOT (BB * HH * SS)   // 131072 = 1<<17

typedef __fp16 hf2 __attribute__((ext_vector_type(2)));
typedef __fp16 h8  __attribute__((ext_vector_type(8)));
typedef float  f4x __attribute__((ext_vector_type(4)));

// ---------------- fast cross-lane helpers ------------
__device__ __forceinline__ int   f2i_(float x) { union { float f; int i; } u; u.f = x; return u.i; }
__device__ __forceinline__ float i2f_(int x)   { union { float f; int i; } u; u.i = x; return u.f; }

// full-wave lane gather: value of lane (pa/4) — pa is a BYTE lane address.
__device__ __forceinline__ float bperm_(int pa, float x) {
    return i2f_(__builtin_amdgcn_ds_bpermute(pa, f2i_(x)));
}

// lane ^ 32 via v_permlane32_swap_b32 (VALU-speed). Semantics-proof select.
__device__ __forceinline__ float half32_(float x) {
#if defined(__has_builtin)
#if __has_builtin(__builtin_amdgcn_permlane32_swap)
    int xi = f2i_(x);
    auto r = __builtin_amdgcn_permlane32_swap(xi, xi, false, false);
    int r0 = (int)r[0], r1 = (int)r[1];
    return i2f_(r0 == xi ? r1 : r0);
#else
    return __shfl_xor(x, 32);
#endif
#else
    return __shfl_xor(x, 32);
#endif
}

// compile-time lane-xor: DPP quad_perm (1..3), ds_swizzle bitmode (<32),
// permlane32 (+swizzle) for >=32.
template<int M> __device__ __forceinline__ float lx(float x) {
    if constexpr (M == 0) {
        return x;
    } else if constexpr (M == 1) {       // quad_perm [1,0,3,2]
        return i2f_(__builtin_amdgcn_update_dpp(0, f2i_(x), 0xB1, 0xF, 0xF, true));
    } else if constexpr (M == 2) {       // quad_perm [2,3,0,1]
        return i2f_(__builtin_amdgcn_update_dpp(0, f2i_(x), 0x4E, 0xF, 0xF, true));
    } else if constexpr (M == 3) {       // quad_perm [3,2,1,0]
        return i2f_(__builtin_amdgcn_update_dpp(0, f2i_(x), 0x1B, 0xF, 0xF, true));
    } else if constexpr (M < 32) {       // ds_swizzle bitmode: xor<<10 | and=0x1F
        return i2f_(__builtin_amdgcn_ds_swizzle(f2i_(x), (M << 10) | 0x1F));
    } else {
        return lx<M & 31>(half32_(x));
    }
}

// full 64-lane sum reduce (bitwise same order as shfl_xor 32,16,8,4,2,1 chain
// would not be; we keep the ORIGINAL order 32..1 to match prior absmax=0)
__device__ __forceinline__ float wsum64_(float v) {
    v += lx<32>(v);
    v += lx<16>(v);
    v += lx<8>(v);
    v += lx<4>(v);
    v += lx<2>(v);
    v += lx<1>(v);
    return v;
}

// ---------------- fused embed + q,k,v projection (layer 0) ------------------
// 4 rows/block. Computes embedding + positional encoding in-block (identical
// expressions to the old k_embed -> bitwise-identical h), writes h, then the
// l=0 qkv projections. Outputs: qh [BHS][8] f16 (pre-scaled), kh, vt.
__global__ __launch_bounds__(64) void k_qkv0(const float* __restrict__ x,
                                             const float* __restrict__ Wemb,
                                             const float* __restrict__ bemb,
                                             const float* __restrict__ Wq, const float* __restrict__ bq,
                                             const float* __restrict__ Wk, const float* __restrict__ bk,
                                             const float* __restrict__ Wv, const float* __restrict__ bv,
                                             hf2* __restrict__ qh, hf2* __restrict__ kh,
                                             hf2* __restrict__ vt, float* __restrict__ h) {
    __shared__ float hrow[4][DD];
    int d   = threadIdx.x;
    int bs0 = blockIdx.x * 4;
    // ---- embed + PE for my column d, 4 rows ----
    {
        int i = d >> 1;
        float div = expf((float)(2 * i) * (-9.210340371976184f / 64.0f));
#pragma unroll
        for (int r = 0; r < 4; ++r) {
            int bs = bs0 + r;
            int s  = bs & (SS - 1);
            const float* xr = x + bs * NF;
            float acc = bemb[d];
#pragma unroll
            for (int f = 0; f < NF; ++f) acc += xr[f] * Wemb[f * DD + d];
            float ang = (float)s * div;
            float pe = (d & 1) ? cosf(ang) : sinf(ang);
            float hv = acc + pe;
            hrow[r][d] = hv;
            h[bs * DD + d] = hv;
        }
    }
    __syncthreads();
    const float* wq = Wq;                 // l = 0
    const float* wk = Wk;
    const float* wv = Wv;
    float aq[4], ak[4], av[4];
    float bqv = bq[d], bkv = bk[d], bvv = bv[d];
#pragma unroll
    for (int r = 0; r < 4; ++r) { aq[r] = bqv; ak[r] = bkv; av[r] = bvv; }
#pragma unroll 4
    for (int i = 0; i < DD; ++i) {
        float wqv = wq[i * DD + d], wkv = wk[i * DD + d], wvv = wv[i * DD + d];
#pragma unroll
        for (int r = 0; r < 4; ++r) {
            float hv = hrow[r][i];
            aq[r] += hv * wqv; ak[r] += hv * wkv; av[r] += hv * wvv;
        }
    }
    int hh = d >> 3, hd = d & 7;
    const float qs = 0.3535533906f;
    float aqp[4], akp[4];
#pragma unroll
    for (int r = 0; r < 4; ++r) { aqp[r] = lx<1>(aq[r]); akp[r] = lx<1>(ak[r]); }
    if ((hd & 1) == 0) {
#pragma unroll
        for (int r = 0; r < 4; ++r) {
            int bs = bs0 + r;
            int b = bs >> 10, s = bs & 1023;
            int bhs = ((b * HH + hh) << 10) | s;
            qh[bhs * 4 + (hd >> 1)] = __builtin_amdgcn_cvt_pkrtz(aq[r] * qs, aqp[r] * qs);
            kh[bhs * 4 + (hd >> 1)] = __builtin_amdgcn_cvt_pkrtz(ak[r], akp[r]);
        }
    }
    {
        int b = bs0 >> 10, s0 = bs0 & 1023;
        int vrow = (b * HH + hh) * 8 + hd;
        hf2* vp = vt + vrow * 512 + (s0 >> 1);
        vp[0] = __builtin_amdgcn_cvt_pkrtz(av[0], av[1]);
        vp[1] = __builtin_amdgcn_cvt_pkrtz(av[2], av[3]);
    }
}

// ---------------- attention via MFMA (swapped-operand, LDS-free) ------------
__global__ __launch_bounds__(256) void k_attn(const float4* __restrict__ qh4,
                                              const float4* __restrict__ kh4,
                                              const float4* __restrict__ vt4,
                                              float* __restrict__ Ao) {
    int bh  = blockIdx.x;             // 0..127
    int sb  = blockIdx.y;             // 0..15
    int tid = threadIdx.x;
    int wv  = tid >> 6;
    int L   = tid & 63;
    int m = L & 15, quad = L >> 4;
    union U { float4 f; h8 h; };
    h8 hz = {0,0,0,0,0,0,0,0};
    h8 bQ = hz;
    if (quad == 0) { U u; u.f = qh4[(bh << 10) | (sb * 64 + wv * 16 + m)]; bQ = u.h; }
    int kmap = 8 * (m >> 2) + (m & 3);
    const float4* kbase = kh4 + (bh << 10);
    const float4* vbase = vt4 + ((bh * 8 + (m & 7)) << 7);
    f4x Oacc = {0.f, 0.f, 0.f, 0.f};
    float ls = 0.f;
    for (int kc = 0; kc < 32; ++kc) {
        h8 aK0 = hz, aK1 = hz;
        if (quad == 0) {
            U u0, u1;
            u0.f = kbase[kc * 32 + kmap];
            u1.f = kbase[kc * 32 + kmap + 4];
            aK0 = u0.h; aK1 = u1.h;
        }
        f4x S0 = {0.f,0.f,0.f,0.f}, S1 = {0.f,0.f,0.f,0.f};
        S0 = __builtin_amdgcn_mfma_f32_16x16x32_f16(aK0, bQ, S0, 0, 0, 0);
        S1 = __builtin_amdgcn_mfma_f32_16x16x32_f16(aK1, bQ, S1, 0, 0, 0);
        float p0 = __expf(S0[0]), p1 = __expf(S0[1]);
        float p2 = __expf(S0[2]), p3 = __expf(S0[3]);
        float p4 = __expf(S1[0]), p5 = __expf(S1[1]);
        float p6 = __expf(S1[2]), p7 = __expf(S1[3]);
        ls += (p0 + p1 + p2 + p3) + (p4 + p5 + p6 + p7);
        hf2 c0 = __builtin_amdgcn_cvt_pkrtz(p0, p1);
        hf2 c1 = __builtin_amdgcn_cvt_pkrtz(p2, p3);
        hf2 c2 = __builtin_amdgcn_cvt_pkrtz(p4, p5);
        hf2 c3 = __builtin_amdgcn_cvt_pkrtz(p6, p7);
        h8 aP;
        aP[0] = c0[0]; aP[1] = c0[1]; aP[2] = c1[0]; aP[3] = c1[1];
        aP[4] = c2[0]; aP[5] = c2[1]; aP[6] = c3[0]; aP[7] = c3[1];
        h8 bV = hz;
        if (m < 8) {
            U uv; uv.f = vbase[kc * 4 + quad];
            bV = uv.h;
        }
        Oacc = __builtin_amdgcn_mfma_f32_16x16x32_f16(aP, bV, Oacc, 0, 0, 0);
    }
    ls += lx<16>(ls);
    ls += lx<32>(ls);
    float d0 = bperm_((4 * quad + 0) << 2, ls);
    float d1 = bperm_((4 * quad + 1) << 2, ls);
    float d2 = bperm_((4 * quad + 2) << 2, ls);
    float d3 = bperm_((4 * quad + 3) << 2, ls);
    if (m < 8) {
        int srow = sb * 64 + wv * 16 + quad * 4;
        int base = (((bh << 10) | srow) << 3) + m;
        Ao[base]      = Oacc[0] / d0;
        Ao[base + 8]  = Oacc[1] / d1;
        Ao[base + 16] = Oacc[2] / d2;
        Ao[base + 24] = Oacc[3] / d3;
    }
}

// ---------------- fused mid: Oproj + LN1 + FFN1 + FFN2 + LN2 [+ qkv(l+1)] ---
// 128 threads, 4 rows/block. If fuse!=0, also computes the NEXT layer's
// q,k,v projections from the freshly computed h rows (wave0: q+k, wave1: v)
// — identical FMA order to the standalone k_qkv, so bitwise-identical.
__global__ __launch_bounds__(128) void k_mid(const float* __restrict__ Ao,
                                             const float* __restrict__ Wo, const float* __restrict__ bo,
                                             const float* __restrict__ g1, const float* __restrict__ b1,
                                             const float* __restrict__ Wf1, const float* __restrict__ bf1,
                                             const float* __restrict__ Wf2, const float* __restrict__ bf2,
                                             const float* __restrict__ g2, const float* __restrict__ b2,
                                             float* __restrict__ h, int l, int fuse,
                                             const float* __restrict__ Wq, const float* __restrict__ bq,
                                             const float* __restrict__ Wk, const float* __restrict__ bk,
                                             const float* __restrict__ Wv, const float* __restrict__ bv,
                                             hf2* __restrict__ qh, hf2* __restrict__ kh,
                                             hf2* __restrict__ vt) {
    __shared__ float orow[4][DD];
    __shared__ float h1s[4][DD];
    __shared__ float frow[4][FFD];
    __shared__ float hfin[4][DD];
    int t    = threadIdx.x;
    int d    = t & 63;
    int half = t >> 6;
    int bs0  = blockIdx.x * 4;
    int hh = d >> 3, hd = d & 7;
    int r0 = half * 2, r1 = r0 + 1;

#pragma unroll
    for (int rr = 0; rr < 2; ++rr) {
        int r  = r0 + rr;
        int bs = bs0 + r;
        int b = bs >> 10, s = bs & 1023;
        int bhs = ((b * HH + hh) << 10) | s;
        orow[r][d] = Ao[(bhs << 3) + hd];
    }
    __syncthreads();

    {
        const float* w = Wo + l * DD * DD;
        float bias = bo[l * DD + d];
        float acc0 = bias, acc1 = bias;
#pragma unroll 4
        for (int i = 0; i < DD; ++i) {
            float wv = w[i * DD + d];
            acc0 += orow[r0][i] * wv;
            acc1 += orow[r1][i] * wv;
        }
        float gg = g1[l * DD + d], bb = b1[l * DD + d];
        float accs[2] = {acc0, acc1};
#pragma unroll
        for (int rr = 0; rr < 2; ++rr) {
            int r = r0 + rr;
            float a = accs[rr] + h[(bs0 + r) * DD + d];
            float sum = wsum64_(a);
            float mean = sum * (1.f / 64.f);
            float dx = a - mean;
            float vs = wsum64_(dx * dx);
            float rstd = rsqrtf(vs * (1.f / 64.f) + 1e-5f);
            h1s[r][d] = dx * rstd * gg + bb;
        }
    }
    __syncthreads();

    {
        const float* w = Wf1 + l * DD * FFD;
        float bv_ = bf1[l * FFD + t];
        float a0 = bv_, a1 = bv_, a2 = bv_, a3 = bv_;
#pragma unroll 4
        for (int i = 0; i < DD; ++i) {
            float wv = w[i * FFD + t];
            a0 += h1s[0][i]*wv; a1 += h1s[1][i]*wv;
            a2 += h1s[2][i]*wv; a3 += h1s[3][i]*wv;
        }
        frow[0][t] = fmaxf(a0, 0.f); frow[1][t] = fmaxf(a1, 0.f);
        frow[2][t] = fmaxf(a2, 0.f); frow[3][t] = fmaxf(a3, 0.f);
    }
    __syncthreads();

    {
        const float* w = Wf2 + l * FFD * DD;
        float bias = bf2[l * DD + d];
        float acc0 = bias, acc1 = bias;
#pragma unroll 4
        for (int i = 0; i < FFD; ++i) {
            float wv = w[i * DD + d];
            acc0 += frow[r0][i] * wv;
            acc1 += frow[r1][i] * wv;
        }
        float gg = g2[l * DD + d], bb = b2[l * DD + d];
        float accs[2] = {acc0, acc1};
#pragma unroll
        for (int rr = 0; rr < 2; ++rr) {
            int r = r0 + rr;
            float a = accs[rr] + h1s[r][d];
            float sum = wsum64_(a);
            float mean = sum * (1.f / 64.f);
            float dx = a - mean;
            float vs = wsum64_(dx * dx);
            float rstd = rsqrtf(vs * (1.f / 64.f) + 1e-5f);
            float hv = dx * rstd * gg + bb;
            hfin[r][d] = hv;
            h[(bs0 + r) * DD + d] = hv;
        }
    }

    if (!fuse) return;

    // ---- fused q,k,v projection for layer l+1 from hfin ----
    __syncthreads();
    const int l1 = l + 1;
    if (t < 64) {
        const float* wq = Wq + l1 * DD * DD;
        const float* wk = Wk + l1 * DD * DD;
        float aq[4], ak[4];
        float bqv = bq[l1 * DD + d], bkv = bk[l1 * DD + d];
#pragma unroll
        for (int r = 0; r < 4; ++r) { aq[r] = bqv; ak[r] = bkv; }
#pragma unroll 4
        for (int i = 0; i < DD; ++i) {
            float wqv = wq[i * DD + d], wkv = wk[i * DD + d];
#pragma unroll
            for (int r = 0; r < 4; ++r) {
                float hv = hfin[r][i];
                aq[r] += hv * wqv; ak[r] += hv * wkv;
            }
        }
        const float qs = 0.3535533906f;
        float aqp[4], akp[4];
#pragma unroll
        for (int r = 0; r < 4; ++r) { aqp[r] = lx<1>(aq[r]); akp[r] = lx<1>(ak[r]); }
        if ((hd & 1) == 0) {
#pragma unroll
            for (int r = 0; r < 4; ++r) {
                int bs = bs0 + r;
                int b = bs >> 10, s = bs & 1023;
                int bhs = ((b * HH + hh) << 10) | s;
                qh[bhs * 4 + (hd >> 1)] = __builtin_amdgcn_cvt_pkrtz(aq[r] * qs, aqp[r] * qs);
                kh[bhs * 4 + (hd >> 1)] = __builtin_amdgcn_cvt_pkrtz(ak[r], akp[r]);
            }
        }
    } else {
        const float* wv = Wv + l1 * DD * DD;
        float av[4];
        float bvv = bv[l1 * DD + d];
#pragma unroll
        for (int r = 0; r < 4; ++r) av[r] = bvv;
#pragma unroll 4
        for (int i = 0; i < DD; ++i) {
            float wvv = wv[i * DD + d];
#pragma unroll
            for (int r = 0; r < 4; ++r) av[r] += hfin[r][i] * wvv;
        }
        int b = bs0 >> 10, s0 = bs0 & 1023;
        int vrow = (b * HH + hh) * 8 + hd;
        hf2* vp = vt + vrow * 512 + (s0 >> 1);
        vp[0] = __builtin_amdgcn_cvt_pkrtz(av[0], av[1]);
        vp[1] = __builtin_amdgcn_cvt_pkrtz(av[2], av[3]);
    }
}

// ---------------- fused tail: pool + head + quantum circuit + eigensolver ---
// 256 threads: all threads cooperatively mean-pool h over S, then wave 0
// (t<64) runs the I$-resident rolled circuit/Jacobi. Barriers are at top
// level so all 256 threads reach them.
__global__ __launch_bounds__(256) void k_tail(const float* __restrict__ h,
                                              const float* __restrict__ Wp1, const float* __restrict__ bp1,
                                              const float* __restrict__ Wp2, const float* __restrict__ bp2,
                                              const float* __restrict__ qw,
                                              float* __restrict__ out) {
    __shared__ float part[4][DD];
    __shared__ float pool_s[DD];
    __shared__ float hid[32];
    __shared__ float ang_s[NQ];
    __shared__ float ucoef[QLAY * 16][8];
    __shared__ float2 Ps2[256];
    int b = blockIdx.x; int t = threadIdx.x;
    int L = t;                        // lane id within wave 0 when t<64
    int lb4 = (t & 63) << 2;

    // ---- pooling: 4 chunks x 64 d, 256 rows each ----
    {
        int d = t & 63, ch = t >> 6;
        const float* hp = h + (b * SS + ch * 256) * DD + d;
        float acc = 0.f;
#pragma unroll 8
        for (int s = 0; s < 256; ++s) acc += hp[s * DD];
        part[ch][d] = acc;
    }
    __syncthreads();
    if (t < 64) pool_s[t] = (part[0][t] + part[1][t] + part[2][t] + part[3][t]) * (1.f / 1024.f);
    __syncthreads();
    if (t < 32) {
        float a = bp1[t];
#pragma unroll 8
        for (int i = 0; i < DD; ++i) a += pool_s[i] * Wp1[i * 32 + t];
        hid[t] = fmaxf(a, 0.f);
    }
    __syncthreads();
    if (t < NQ) {
        float a = bp2[t];
#pragma unroll 8
        for (int j = 0; j < 32; ++j) a += hid[j] * Wp2[j * NQ + t];
        ang_s[t] = tanhf(a) * 3.14159265358979f;
    }
    __syncthreads();

    // ---- per-gate 2x2 matrix table (lane-parallel, one-shot) ----
    if (t < QLAY * 16) {
        int l = t >> 4, g8 = t & 15, w = g8 & 7;
        float u00r, u00i, u01r, u01i, u10r, u10i, u11r, u11i;
        if (g8 < 8) {
            float ha = 0.5f * ang_s[w];
            float c = __cosf(ha), s = __sinf(ha);
            u00r = c;   u00i = 0.f; u01r = 0.f; u01i = -s;
            u10r = 0.f; u10i = -s;  u11r = c;   u11i = 0.f;
        } else {
            const float* p3 = qw + (l * NQ + w) * 3;
            float phi = p3[0], th = p3[1], om = p3[2];
            float ct = __cosf(0.5f * th), st = __sinf(0.5f * th);
            float al = 0.5f * (phi + om), be = 0.5f * (phi - om);
            float ca = __cosf(al), sa = __sinf(al), cb = __cosf(be), sb = __sinf(be);
            u00r =  ct * ca; u00i = -ct * sa;
            u01r = -st * cb; u01i = -st * sb;
            u10r =  st * cb; u10i = -st * sb;
            u11r =  ct * ca; u11i =  ct * sa;
        }
        float* up = ucoef[t];
        up[0] = u00r; up[1] = u00i; up[2] = u01r; up[3] = u01i;
        up[4] = u10r; up[5] = u10i; up[6] = u11r; up[7] = u11i;
    }
    __syncthreads();

    // ---- quantum circuit (rolled, table-driven) — wave 0 only ----
    float ar[4], ai[4];
#pragma unroll
    for (int r = 0; r < 4; ++r) { ar[r] = 0.f; ai[r] = 0.f; }
    if (L == 0) ar[0] = 1.f;

    if (t < 64) {
#pragma unroll 1
        for (int l = 0; l < QLAY; ++l) {
#pragma unroll 1
            for (int g8 = 0; g8 < 16; ++g8) {
                const float* up = ucoef[(l << 4) | g8];
                float u00r = up[0], u00i = up[1], u01r = up[2], u01i = up[3];
                float u10r = up[4], u10i = up[5], u11r = up[6], u11i = up[7];
                int p = 7 - (g8 & 7);
                if (p >= 6) {
#pragma unroll
                    for (int pi_ = 0; pi_ < 2; ++pi_) {
                        int lo = (p == 7) ? pi_ : pi_ * 2;
                        int hi = (p == 7) ? pi_ + 2 : pi_ * 2 + 1;
                        float r0 = ar[lo], m0 = ai[lo], r1 = ar[hi], m1 = ai[hi];
                        ar[lo] = u00r*r0 - u00i*m0 + u01r*r1 - u01i*m1;
                        ai[lo] = u00r*m0 + u00i*r0 + u01r*m1 + u01i*r1;
                        ar[hi] = u10r*r0 - u10i*m0 + u11r*r1 - u11i*m1;
                        ai[hi] = u10r*m0 + u10i*r0 + u11r*m1 + u11i*r1;
                    }
                } else {
                    int pa  = lb4 ^ (4 << p);
                    int bit = (L >> p) & 1;
                    float car = bit ? u11r : u00r, cai = bit ? u11i : u00i;
                    float cpr = bit ? u10r : u01r, cpi = bit ? u10i : u01i;
#pragma unroll
                    for (int r = 0; r < 4; ++r) {
                        float pre = bperm_(pa, ar[r]);
                        float pim = bperm_(pa, ai[r]);
                        float nr = car*ar[r] - cai*ai[r] + cpr*pre - cpi*pim;
                        float ni = car*ai[r] + cai*ar[r] + cpr*pim + cpi*pre;
                        ar[r] = nr; ai[r] = ni;
                    }
                }
            }
            // ---- CNOT ladder ----
            { float t0=ar[2]; ar[2]=ar[3]; ar[3]=t0; t0=ai[2]; ai[2]=ai[3]; ai[3]=t0; }
            ar[1] = half32_(ar[1]); ai[1] = half32_(ai[1]);
            ar[3] = half32_(ar[3]); ai[3] = half32_(ai[3]);
#pragma unroll 1
            for (int w = 2; w <= 6; ++w) {
                int pc = 7 - w, pt = 6 - w;
                int pa = lb4 ^ (4 << pt);
                bool ctrl = (L >> pc) & 1;
#pragma unroll
                for (int r = 0; r < 4; ++r) {
                    float swr = bperm_(pa, ar[r]);
                    float swi = bperm_(pa, ai[r]);
                    ar[r] = ctrl ? swr : ar[r];
                    ai[r] = ctrl ? swi : ai[r];
                }
            }
            {
                bool ctrl = L & 1;
                float n0r = ctrl ? ar[2] : ar[0], n2r = ctrl ? ar[0] : ar[2];
                float n0i = ctrl ? ai[2] : ai[0], n2i = ctrl ? ai[0] : ai[2];
                float n1r = ctrl ? ar[3] : ar[1], n3r = ctrl ? ar[1] : ar[3];
                float n1i = ctrl ? ai[3] : ai[1], n3i = ctrl ? ai[1] : ai[3];
                ar[0]=n0r; ar[1]=n1r; ar[2]=n2r; ar[3]=n3r;
                ai[0]=n0i; ai[1]=n1i; ai[2]=n2i; ai[3]=n3i;
            }
        }

        // ---- <Z_w>, w=0..2 ----
        {
            float p0 = ar[0]*ar[0]+ai[0]*ai[0];
            float p1 = ar[1]*ar[1]+ai[1]*ai[1];
            float p2 = ar[2]*ar[2]+ai[2]*ai[2];
            float p3 = ar[3]*ar[3]+ai[3]*ai[3];
            float z0 = p0 + p1 - p2 - p3;
            float z1 = p0 - p1 + p2 - p3;
            float zs = p0 + p1 + p2 + p3;
            float z2 = (L & 32) ? -zs : zs;
#pragma unroll 1
            for (int off = 1; off < 64; off <<= 1) {
                int pa = lb4 ^ (off << 2);
                z0 += bperm_(pa, z0);
                z1 += bperm_(pa, z1);
                z2 += bperm_(pa, z2);
            }
            if (L == 0) {
                out[b * NC + 0] = z0;
                out[b * NC + 1] = z1;
                out[b * NC + 2] = z2;
            }
        }

        // ---- hand off psi through LDS ----
#pragma unroll
        for (int r = 0; r < 4; ++r) Ps2[(r << 6) | L] = make_float2(ar[r], ai[r]);
    }
    __syncthreads();

    if (t < 64) {
        int c   = L >> 2;
        int seg = L & 3;
        float gr[4], gi[4];
#pragma unroll
        for (int j = 0; j < 4; ++j) {
            float2 tv = Ps2[(seg * 4 + j) * 16 + c];
            gr[j] = tv.x; gi[j] = tv.y;
        }
        float alm = 0.f;
#pragma unroll
        for (int j = 0; j < 4; ++j) alm += gr[j]*gr[j] + gi[j]*gi[j];
        alm += lx<1>(alm);
        alm += lx<2>(alm);

#pragma unroll 1
        for (int sweep = 0; sweep < NSWEEP; ++sweep) {
#pragma unroll 1
            for (int m = 1; m <= 15; ++m) {
                int pa = lb4 ^ (m << 4);
                float pgr[4], pgi[4];
#pragma unroll
                for (int j = 0; j < 4; ++j) {
                    pgr[j] = bperm_(pa, gr[j]);
                    pgi[j] = bperm_(pa, gi[j]);
                }
                float bep = bperm_(pa, alm);
                float d = 0.f, e = 0.f;
#pragma unroll
                for (int j = 0; j < 4; ++j) {
                    d += gr[j]*pgr[j] + gi[j]*pgi[j];
                    e += gr[j]*pgi[j] - gi[j]*pgr[j];
                }
                d += lx<1>(d); e += lx<1>(e);
                d += lx<2>(d); e += lx<2>(e);
                float g2 = d*d + e*e;
                float cth = 1.f, sth = 0.f, cph = 1.f, sph = 0.f, gn = 0.f;
                if (g2 > 1e-26f) {
                    gn = __builtin_amdgcn_sqrtf(g2);
                    float ginv = __builtin_amdgcn_rcpf(gn);
                    cph = d * ginv; sph = -e * ginv;
                    float tau = (alm - bep) * (0.5f * ginv);
                    float tt = ((tau >= 0.f) ? 1.f : -1.f) *
                               __builtin_amdgcn_rcpf(fabsf(tau) + __builtin_amdgcn_sqrtf(1.f + tau*tau));
                    cth = __builtin_amdgcn_rsqf(1.f + tt*tt);
                    sth = tt * cth;
                }
#pragma unroll
                for (int j = 0; j < 4; ++j) {
                    float er = cph*pgr[j] - sph*pgi[j];
                    float ei = cph*pgi[j] + sph*pgr[j];
                    gr[j] = cth * gr[j] + sth * er;
                    gi[j] = cth * gi[j] + sth * ei;
                }
                alm = cth*cth*alm + sth*sth*bep + 2.f*cth*sth*gn;
            }
        }

        float alm2 = 0.f;
#pragma unroll
        for (int j = 0; j < 4; ++j) alm2 += gr[j]*gr[j] + gi[j]*gi[j];
        alm2 += lx<1>(alm2);
        alm2 += lx<2>(alm2);

        float ev = fminf(fmaxf(alm2, 1e-10f), 1.0f);
        float term = -ev * __logf(ev);
#pragma unroll 1
        for (int off = 4; off < 64; off <<= 1) term += bperm_(lb4 ^ (off << 2), term);
        if (L == 0) out[BB * NC + b] = term;
    }
}

extern "C" void kernel_launch(void* const* d_in, const int* in_sizes, int n_in,
                              void* d_out, int out_size, void* d_ws, size_t ws_size,
                              hipStream_t stream) {
    const float* x    = (const float*)d_in[0];
    const float* Wemb = (const float*)d_in[1];
    const float* bemb = (const float*)d_in[2];
    const float* Wq   = (const float*)d_in[3];
    const float* bq   = (const float*)d_in[4];
    const float* Wk   = (const float*)d_in[5];
    const float* bk   = (const float*)d_in[6];
    const float* Wv   = (const float*)d_in[7];
    const float* bv   = (const float*)d_in[8];
    const float* Wo   = (const float*)d_in[9];
    const float* bo   = (const float*)d_in[10];
    const float* ln1g = (const float*)d_in[11];
    const float* ln1b = (const float*)d_in[12];
    const float* ln2g = (const float*)d_in[13];
    const float* ln2b = (const float*)d_in[14];
    const float* Wf1  = (const float*)d_in[15];
    const float* bf1  = (const float*)d_in[16];
    const float* Wf2  = (const float*)d_in[17];
    const float* bf2  = (const float*)d_in[18];
    const float* Wp1  = (const float*)d_in[19];
    const float* bp1  = (const float*)d_in[20];
    const float* Wp2  = (const float*)d_in[21];
    const float* bp2  = (const float*)d_in[22];
    const float* qwts = (const float*)d_in[23];
    float* out = (float*)d_out;

    const size_t M = 1u << 20;           // 1M floats = B*S*D
    float* ws   = (float*)d_ws;
    float* h    = ws;                            // 1M floats
    hf2*   qh   = (hf2*)(ws + M);                // 0.5M floats (BHS*8 halves)
    hf2*   kh   = (hf2*)(ws + M + M / 2);        // 0.5M floats
    hf2*   vt   = (hf2*)(ws + 2 * M);            // 0.5M floats
    float* Ao   = ws + 2 * M + M / 2;            // 1M floats (BHS*8)

    // 6 launches (was 9): embed fused into qkv0; qkv1 fused into mid(l=0);
    // pool fused into tail.
    k_qkv0<<<BB * SS / 4, 64, 0, stream>>>(x, Wemb, bemb, Wq, bq, Wk, bk, Wv, bv,
                                           qh, kh, vt, h);
    k_attn<<<dim3(BB * HH, 16), 256, 0, stream>>>((const float4*)qh, (const float4*)kh,
                                                  (const float4*)vt, Ao);
    k_mid<<<BB * SS / 4, 128, 0, stream>>>(Ao, Wo, bo, ln1g, ln1b,
                                           Wf1, bf1, Wf2, bf2, ln2g, ln2b, h, 0, 1,
                                           Wq, bq, Wk, bk, Wv, bv, qh, kh, vt);
    k_attn<<<dim3(BB * HH, 16), 256, 0, stream>>>((const float4*)qh, (const float4*)kh,
                                                  (const float4*)vt, Ao);
    k_mid<<<BB * SS / 4, 128, 0, stream>>>(Ao, Wo, bo, ln1g, ln1b,
                                           Wf1, bf1, Wf2, bf2, ln2g, ln2b, h, 1, 0,
                                           Wq, bq, Wk, bk, Wv, bv, qh, kh, vt);
    k_tail<<<BB, 256, 0, stream>>>(h, Wp1, bp1, Wp2, bp2, qwts, out);
}